// Round 1
// 440.777 us; speedup vs baseline: 1.0051x; 1.0051x over previous
//
#include <hip/hip_runtime.h>

#define B_   2
#define S_   2048
#define HID_ 2048
#define NH_  16
#define HD_  128
#define MAXTOK_ 2048

typedef float  f32x4  __attribute__((ext_vector_type(4)));
typedef __bf16 bf16x8 __attribute__((ext_vector_type(8)));

__device__ __forceinline__ unsigned short f2bf(float f) {
  union { float fv; unsigned u; } v; v.fv = f;
  unsigned r = v.u + 0x7FFFu + ((v.u >> 16) & 1u);  // RNE
  return (unsigned short)(r >> 16);
}
__device__ __forceinline__ float bf2f(unsigned short h) {
  union { unsigned u; float fv; } v; v.u = ((unsigned)h) << 16;
  return v.fv;
}

// async global->LDS, 16B per lane (GEMM staging only; LDS dst must be contiguous)
__device__ __forceinline__ void gload16(const void* g, void* lds) {
  __builtin_amdgcn_global_load_lds(
      (const __attribute__((address_space(1))) void*)g,
      (__attribute__((address_space(3))) void*)lds, 16, 0, 0);
}

// ---------------- fused cast fp32 -> bf16 for hidden + 4 weights ----------------
#define H4_ (B_ * S_ * HID_ / 4)
#define W4_ (HID_ * HID_ / 4)
__global__ void cast_all(const float* __restrict__ h,  const float* __restrict__ wq,
                         const float* __restrict__ wk, const float* __restrict__ wv,
                         const float* __restrict__ wo,
                         unsigned short* __restrict__ xb,  unsigned short* __restrict__ wqb,
                         unsigned short* __restrict__ wkb, unsigned short* __restrict__ wvb,
                         unsigned short* __restrict__ wob) {
  const int total = H4_ + 4 * W4_;
  int i = blockIdx.x * blockDim.x + threadIdx.x;
  int stride = gridDim.x * blockDim.x;
  for (; i < total; i += stride) {
    const float* src; unsigned short* dst; int j;
    if (i < H4_) { src = h; dst = xb; j = i; }
    else {
      int k = i - H4_, wsel = k >> 20;  // W4_ = 2^20
      j = k & (W4_ - 1);
      src = (wsel == 0) ? wq : (wsel == 1) ? wk : (wsel == 2) ? wv : wo;
      dst = (wsel == 0) ? wqb : (wsel == 1) ? wkb : (wsel == 2) ? wvb : wob;
    }
    float4 v = ((const float4*)src)[j];
    ushort4 o;
    o.x = f2bf(v.x); o.y = f2bf(v.y); o.z = f2bf(v.z); o.w = f2bf(v.w);
    ((ushort4*)dst)[j] = o;
  }
}

// ---------------- fused QKV projection: 256x256 tile, BK=64, 8-phase schedule ----------------
// T3+T4 (phase-split + counted vmcnt) + T2 (st_16x32 LDS swizzle) + T5 (setprio).
// C[4096,6144] = X[4096,2048] * Wqkv[6144,2048]^T, epilogue scatters to Qb/Kb/Vtmp.
//
// 8 waves in 2(M)x4(N) grid, each owns a 128x64 output slab = acc[8][4] f32x4.
// LDS: double-buffered 256x64 bf16 A and B tiles = 128 KiB, 1 block/CU.
// Per K-tile: 4 phases (mh,np) in zigzag order (0,0)(1,0)(1,1)(0,1) so A/B frags
// are reused across adjacent phases. Each phase: ds_read frags -> issue 2
// global_load_lds (next tile) -> barrier -> setprio(1) 16xMFMA setprio(0) ->
// [counted vmcnt] -> barrier.
// Staging issue order for tile t+1 (during tile t): B0,B1 | B2,B3 | A0,A2 | A1,A3.
// Need-by: {B0..B3,A0,A2} at ph0 (= oldest 6 of 8 in flight -> vmcnt(2) in ph3),
//          {A1,A3} at ph1 (-> vmcnt(2) in ph0; outstanding then = A1,A3,B0',B1').
// Never drains to 0 in the main loop.
//
// Swizzle (rule #21, both-sides): LDS layout is linear [256 rows][64 cols];
// read addr byte ^= ((row>>2)&1)<<5, and staging pre-swizzles the GLOBAL source
// column by the same involution so global_load_lds's linear write lands swizzled.
#define QKV_STG(gp, lp, rb) gload16((gp) + (size_t)(rb) * 2048, (lp) + (rb) * 64)

#define QKV_LOADA(MH) do { \
  _Pragma("unroll") \
  for (int mi_ = 0; mi_ < 4; ++mi_) { \
    const char* rp_ = (const char*)Acur + (size_t)((wm + (MH) * 64 + mi_ * 16 + rowq) * 128); \
    af[mi_][0] = *(const bf16x8*)(rp_ + cb0); \
    af[mi_][1] = *(const bf16x8*)(rp_ + cb1); \
  } } while (0)

#define QKV_LOADB(NP) do { \
  _Pragma("unroll") \
  for (int ni_ = 0; ni_ < 2; ++ni_) { \
    const char* rp_ = (const char*)Bcur + (size_t)((wn + (NP) * 32 + ni_ * 16 + rowq) * 128); \
    bfr[ni_][0] = *(const bf16x8*)(rp_ + cb0); \
    bfr[ni_][1] = *(const bf16x8*)(rp_ + cb1); \
  } } while (0)

#define QKV_MFMA(MH, NP) do { \
  _Pragma("unroll") \
  for (int mi_ = 0; mi_ < 4; ++mi_) { \
    _Pragma("unroll") \
    for (int ni_ = 0; ni_ < 2; ++ni_) { \
      f32x4 c_ = acc[(MH) * 4 + mi_][(NP) * 2 + ni_]; \
      c_ = __builtin_amdgcn_mfma_f32_16x16x32_bf16(af[mi_][0], bfr[ni_][0], c_, 0, 0, 0); \
      c_ = __builtin_amdgcn_mfma_f32_16x16x32_bf16(af[mi_][1], bfr[ni_][1], c_, 0, 0, 0); \
      acc[(MH) * 4 + mi_][(NP) * 2 + ni_] = c_; \
    } } } while (0)

#define QKV_BAR    asm volatile("s_barrier" ::: "memory")
#define QKV_VMC2   asm volatile("s_waitcnt vmcnt(2)" ::: "memory")
#define QKV_VMC0   asm volatile("s_waitcnt vmcnt(0)" ::: "memory")

__global__ __launch_bounds__(512, 2)
void gemm_qkv(const unsigned short* __restrict__ A,
              const unsigned short* __restrict__ Bw,
              unsigned short* __restrict__ Qb,
              unsigned short* __restrict__ Kb,
              unsigned short* __restrict__ Vtmp) {
  const int K = HID_;       // 2048
  const int NT = K / 64;    // 32 K-tiles
  __shared__ __align__(16) unsigned short As[2][256 * 64];
  __shared__ __align__(16) unsigned short Bs[2][256 * 64];

  const int tid = threadIdx.x, lane = tid & 63, w = tid >> 6;
  const int n0 = blockIdx.x * 256, m0 = blockIdx.y * 256;
  const int wm = (w >> 2) * 128, wn = (w & 3) * 64;
  const int rowq = lane & 15, klane = lane >> 4;
  // read-side swizzle bit: ((row>>2)&1)<<5 == ((rowq>>2)&1)<<5 (row bases are x16/x32/x64)
  const int sw  = ((rowq >> 2) & 1) << 5;
  const int cb0 = (klane * 16) ^ sw;        // ks=0 column byte, swizzled
  const int cb1 = (64 + klane * 16) ^ sw;   // ks=1
  // staging decomposition: 512 threads x 16B = one 64-row block per call
  const int srow = tid >> 3;                // 0..63
  const int dc8  = (tid & 7) * 8;           // lds col (elements), linear dst
  const int scol = (((tid & 7) * 16) ^ (((srow >> 2) & 1) << 5)) >> 1;  // swizzled global col (elems)

  const unsigned short* Ag = A  + (size_t)(m0 + srow) * K + scol;
  const unsigned short* Bg = Bw + (size_t)(n0 + srow) * K + scol;

  f32x4 acc[8][4];
#pragma unroll
  for (int i = 0; i < 8; ++i)
#pragma unroll
    for (int j = 0; j < 4; ++j)
#pragma unroll
      for (int r = 0; r < 4; ++r) acc[i][j][r] = 0.f;

  bf16x8 af[4][2], bfr[2][2];

  // prologue: stage tile 0 into buffer 0 (same issue order as steady state)
  {
    unsigned short* Al = (unsigned short*)&As[0][0] + srow * 64 + dc8;
    unsigned short* Bl = (unsigned short*)&Bs[0][0] + srow * 64 + dc8;
    QKV_STG(Bg, Bl, 0); QKV_STG(Bg, Bl, 64); QKV_STG(Bg, Bl, 128); QKV_STG(Bg, Bl, 192);
    QKV_STG(Ag, Al, 0); QKV_STG(Ag, Al, 128); QKV_STG(Ag, Al, 64); QKV_STG(Ag, Al, 192);
  }
  QKV_VMC2;   // oldest 6 (B0..B3, A0, A2) landed
  QKV_BAR;

  const unsigned short* Acur = &As[0][0];
  const unsigned short* Bcur = &Bs[0][0];
  unsigned short* Anx = (unsigned short*)&As[1][0];
  unsigned short* Bnx = (unsigned short*)&Bs[1][0];

  for (int t = 0; t < NT - 1; ++t) {
    const int kn = (t + 1) * 64;
    const unsigned short* Agk = Ag + kn;
    const unsigned short* Bgk = Bg + kn;
    unsigned short* Al = Anx + srow * 64 + dc8;
    unsigned short* Bl = Bnx + srow * 64 + dc8;

    // ph0: (mh0,np0) -- read A-low+B-low, stage B0,B1; vmcnt(2) covers ph1's A1,A3
    QKV_LOADA(0); QKV_LOADB(0);
    QKV_STG(Bgk, Bl, 0); QKV_STG(Bgk, Bl, 64);
    QKV_BAR;
    __builtin_amdgcn_s_setprio(1); QKV_MFMA(0, 0); __builtin_amdgcn_s_setprio(0);
    QKV_VMC2;
    QKV_BAR;
    // ph1: (mh1,np0) -- read A-high, reuse B-low, stage B2,B3
    QKV_LOADA(1);
    QKV_STG(Bgk, Bl, 128); QKV_STG(Bgk, Bl, 192);
    QKV_BAR;
    __builtin_amdgcn_s_setprio(1); QKV_MFMA(1, 0); __builtin_amdgcn_s_setprio(0);
    QKV_BAR;
    // ph2: (mh1,np1) -- read B-high, reuse A-high, stage A0,A2
    QKV_LOADB(1);
    QKV_STG(Agk, Al, 0); QKV_STG(Agk, Al, 128);
    QKV_BAR;
    __builtin_amdgcn_s_setprio(1); QKV_MFMA(1, 1); __builtin_amdgcn_s_setprio(0);
    QKV_BAR;
    // ph3: (mh0,np1) -- re-read A-low, reuse B-high, stage A1,A3; vmcnt(2) covers next ph0
    QKV_LOADA(0);
    QKV_STG(Agk, Al, 64); QKV_STG(Agk, Al, 192);
    QKV_BAR;
    __builtin_amdgcn_s_setprio(1); QKV_MFMA(0, 1); __builtin_amdgcn_s_setprio(0);
    QKV_VMC2;
    QKV_BAR;

    { const unsigned short* tp = Acur; Acur = Anx; Anx = (unsigned short*)tp; }
    { const unsigned short* tp = Bcur; Bcur = Bnx; Bnx = (unsigned short*)tp; }
  }

  // tail tile (no staging): ph0 must fully drain (A1,A3 have no younger loads behind them)
  QKV_LOADA(0); QKV_LOADB(0);
  QKV_BAR;
  __builtin_amdgcn_s_setprio(1); QKV_MFMA(0, 0); __builtin_amdgcn_s_setprio(0);
  QKV_VMC0;
  QKV_BAR;
  QKV_LOADA(1);
  QKV_BAR;
  __builtin_amdgcn_s_setprio(1); QKV_MFMA(1, 0); __builtin_amdgcn_s_setprio(0);
  QKV_BAR;
  QKV_LOADB(1);
  QKV_BAR;
  __builtin_amdgcn_s_setprio(1); QKV_MFMA(1, 1); __builtin_amdgcn_s_setprio(0);
  QKV_BAR;
  QKV_LOADA(0);
  QKV_BAR;
  __builtin_amdgcn_s_setprio(1); QKV_MFMA(0, 1); __builtin_amdgcn_s_setprio(0);

  // epilogue scatter (C/D layout: col=lane&15, row=(lane>>4)*4+r)
  const int lr0 = klane * 4;
#pragma unroll
  for (int mi = 0; mi < 8; ++mi)
#pragma unroll
    for (int ni = 0; ni < 4; ++ni)
#pragma unroll
      for (int r = 0; r < 4; ++r) {
        int r_ = m0 + wm + mi * 16 + lr0 + r;
        int c_ = n0 + wn + ni * 16 + rowq;
        float v = acc[mi][ni][r];
        int b = r_ >> 11, s = r_ & 2047;
        int proj = c_ >> 11, cin = c_ & 2047;
        if (proj == 2) {
          Vtmp[(size_t)(b * S_ + s) * HID_ + cin] = f2bf(v);
        } else {
          int hh = cin >> 7, d = cin & 127;
          unsigned short* dst = (proj == 0) ? Qb : Kb;
          dst[(((size_t)(b * NH_ + hh) * S_ + s) * HD_) + d] = f2bf(v);
        }
      }
}

// ---------------- output projection: C[M,N] = A[M,K] * B[N,K]^T, 128x128 tile, BK=32 ----------------
__global__ __launch_bounds__(256, 2)
void gemm_out(const unsigned short* __restrict__ A,
              const unsigned short* __restrict__ Bw,
              float* __restrict__ Cout) {
  const int N = HID_, K = HID_;
  __shared__ __align__(16) unsigned short As[128 * 32];
  __shared__ __align__(16) unsigned short Bs[128 * 32];
  const int tid = threadIdx.x, lane = tid & 63, w = tid >> 6;
  const int n0 = blockIdx.x * 128, m0 = blockIdx.y * 128;
  const int wm = (w & 1) * 64, wn = (w >> 1) * 64;
  const int rowq = lane & 15;
  const int koff = (lane >> 4) * 8;
  const int lr0 = (lane >> 4) * 4;

  f32x4 acc[4][4];
  for (int i = 0; i < 4; ++i)
    for (int j = 0; j < 4; ++j)
      for (int r = 0; r < 4; ++r) acc[i][j][r] = 0.f;

  for (int k0 = 0; k0 < K; k0 += 32) {
    __syncthreads();
    for (int c = 0; c < 2; ++c) {
      int chunk = (w * 2 + c) * 64 + lane;
      int row = chunk >> 2, cc = chunk & 3;
      gload16(A + (size_t)(m0 + row) * K + k0 + cc * 8, As + (w * 2 + c) * 512);
      gload16(Bw + (size_t)(n0 + row) * K + k0 + cc * 8, Bs + (w * 2 + c) * 512);
    }
    __syncthreads();
    bf16x8 af[4], bfv[4];
    for (int i = 0; i < 4; ++i) {
      af[i]  = *(const bf16x8*)&As[(wm + i * 16 + rowq) * 32 + koff];
      bfv[i] = *(const bf16x8*)&Bs[(wn + i * 16 + rowq) * 32 + koff];
    }
    for (int mi = 0; mi < 4; ++mi)
      for (int ni = 0; ni < 4; ++ni)
        acc[mi][ni] = __builtin_amdgcn_mfma_f32_16x16x32_bf16(af[mi], bfv[ni], acc[mi][ni], 0, 0, 0);
  }

  for (int mi = 0; mi < 4; ++mi)
    for (int ni = 0; ni < 4; ++ni)
      for (int r = 0; r < 4; ++r) {
        int r_ = m0 + wm + mi * 16 + lr0 + r;
        int c_ = n0 + wn + ni * 16 + rowq;
        Cout[(size_t)r_ * N + c_] = acc[mi][ni][r];
      }
}

// ---------------- RoPE: table precompute + coalesced apply ----------------
__global__ void rope_table(float2* __restrict__ tbl) {
  int i = blockIdx.x * blockDim.x + threadIdx.x;  // p*64 + d
  if (i >= MAXTOK_ * 64) return;
  int p = i >> 6, d = i & 63;
  float f = __expf(-(float)d * (9.210340371976184f / 64.f));  // 10000^(-d/64)
  float sn, cs;
  __sincosf((float)p * f, &sn, &cs);
  tbl[i] = make_float2(cs, sn);
}

#define QSCALE_ 0.12751744f
__global__ __launch_bounds__(256)
void rope_apply(unsigned short* __restrict__ Qb, unsigned short* __restrict__ Kb,
                const int* __restrict__ pos_ids, const float2* __restrict__ tbl) {
  int i = blockIdx.x * blockDim.x + threadIdx.x;  // bhs*64 + d
  int d = i & 63, bhs = i >> 6;
  int s = bhs & (S_ - 1);
  int b = bhs >> 15;  // NH_*S_ = 32768
  int p = pos_ids[b * S_ + s];
  float2 cssn = tbl[p * 64 + d];
  size_t base = (size_t)bhs * HD_;
  {
    float x1 = bf2f(Qb[base + d]), x2 = bf2f(Qb[base + d + 64]);
    Qb[base + d]      = f2bf((x1 * cssn.x - x2 * cssn.y) * QSCALE_);
    Qb[base + d + 64] = f2bf((x2 * cssn.x + x1 * cssn.y) * QSCALE_);
  }
  {
    float x1 = bf2f(Kb[base + d]), x2 = bf2f(Kb[base + d + 64]);
    Kb[base + d]      = f2bf(x1 * cssn.x - x2 * cssn.y);
    Kb[base + d + 64] = f2bf(x2 * cssn.x + x1 * cssn.y);
  }
}

// ---------------- transpose V: (B,S,HID) bf16 -> (B,NH,HD,S) bf16 ----------------
__global__ __launch_bounds__(256)
void transpose_v(const unsigned short* __restrict__ Vin,
                 unsigned short* __restrict__ Vt) {
  __shared__ unsigned short t[64 * 66];
  const int s0 = blockIdx.x * 64, d0 = blockIdx.y * 64, bh = blockIdx.z;
  const int b = bh >> 4, h = bh & 15;
  for (int it = 0; it < 16; ++it) {
    int lin = it * 256 + threadIdx.x;
    int sl = lin >> 6, dl = lin & 63;
    t[sl * 66 + dl] = Vin[(size_t)(b * S_ + s0 + sl) * HID_ + h * HD_ + d0 + dl];
  }
  __syncthreads();
  for (int it = 0; it < 16; ++it) {
    int lin = it * 256 + threadIdx.x;
    int dl = lin >> 6, sl = lin & 63;
    Vt[((size_t)bh * HD_ + d0 + dl) * S_ + s0 + sl] = t[sl * 66 + dl];
  }
}

// ---------------- fused causal flash attention (v5) ----------------
#define KS_LD 136   // 64x128 K tile, padded (16B-aligned rows, 2-way bank aliasing)
#define VS_LD 72    // 128x64 V^T tile, padded
#define PS_LD 72    // 16x64 P tile per wave, padded (b128-aligned; Ps writes ~4-way)
__global__ __launch_bounds__(256, 2)
void attn_fused(const unsigned short* __restrict__ Qb,
                const unsigned short* __restrict__ Kb,
                const unsigned short* __restrict__ Vt,
                unsigned short* __restrict__ Ob) {
  __shared__ __align__(16) unsigned short Ks[64 * KS_LD];
  __shared__ __align__(16) unsigned short Vts[128 * VS_LD];
  __shared__ __align__(16) unsigned short Ps[4 * 16 * PS_LD];

  const int tid = threadIdx.x, lane = tid & 63, w = tid >> 6;
  const int bh = blockIdx.x;                    // fast dim: spreads heads across XCDs
  const int qt = (gridDim.y - 1) - blockIdx.y;  // descending: longest blocks first (LPT)
  const int q0 = qt * 64;
  const int b = bh >> 4, h = bh & 15;
  const int rowq = lane & 15;
  const int koff = (lane >> 4) * 8;
  const int lr0 = (lane >> 4) * 4;
  const size_t qkbase = (size_t)bh * (S_ * HD_);
  const size_t vbase  = (size_t)bh * (HD_ * S_);

  bf16x8 qf0, qf1, qf2, qf3;
  {
    const unsigned short* qrow = Qb + qkbase + (size_t)(q0 + w * 16 + rowq) * HD_;
    qf0 = *(const bf16x8*)(qrow + 0 * 32 + koff);
    qf1 = *(const bf16x8*)(qrow + 1 * 32 + koff);
    qf2 = *(const bf16x8*)(qrow + 2 * 32 + koff);
    qf3 = *(const bf16x8*)(qrow + 3 * 32 + koff);
  }

  const int krow = tid >> 4, kcol = (tid & 15) * 8;  // K: 16 rows/pass
  const int vrow = tid >> 3, vcol = (tid & 7) * 8;   // V^T: 32 rows/pass
  const unsigned short* kptr = Kb + qkbase + (size_t)krow * HD_ + kcol;
  const unsigned short* vptr = Vt + vbase + (size_t)vrow * S_ + vcol;

  f32x4 oacc[8];
  for (int i = 0; i < 8; ++i)
    for (int r = 0; r < 4; ++r) oacc[i][r] = 0.f;
  float m_r[4] = {-3e38f, -3e38f, -3e38f, -3e38f};
  float l_r[4] = {0.f, 0.f, 0.f, 0.f};

  const int nkt = qt + 1;

  float4 k0, k1, k2, k3, v0, v1, v2, v3;
  k0 = *(const float4*)(kptr + 0 * 16 * HD_);
  k1 = *(const float4*)(kptr + 1 * 16 * HD_);
  k2 = *(const float4*)(kptr + 2 * 16 * HD_);
  k3 = *(const float4*)(kptr + 3 * 16 * HD_);
  v0 = *(const float4*)(vptr + 0 * 32 * S_);
  v1 = *(const float4*)(vptr + 1 * 32 * S_);
  v2 = *(const float4*)(vptr + 2 * 32 * S_);
  v3 = *(const float4*)(vptr + 3 * 32 * S_);

  for (int kt = 0; kt < nkt; ++kt) {
    __syncthreads();  // previous tile's readers done
    *(float4*)&Ks[(krow + 0 * 16) * KS_LD + kcol] = k0;
    *(float4*)&Ks[(krow + 1 * 16) * KS_LD + kcol] = k1;
    *(float4*)&Ks[(krow + 2 * 16) * KS_LD + kcol] = k2;
    *(float4*)&Ks[(krow + 3 * 16) * KS_LD + kcol] = k3;
    *(float4*)&Vts[(vrow + 0 * 32) * VS_LD + vcol] = v0;
    *(float4*)&Vts[(vrow + 1 * 32) * VS_LD + vcol] = v1;
    *(float4*)&Vts[(vrow + 2 * 32) * VS_LD + vcol] = v2;
    *(float4*)&Vts[(vrow + 3 * 32) * VS_LD + vcol] = v3;
    if (kt + 1 < nkt) {
      const unsigned short* kp = kptr + (size_t)(kt + 1) * 64 * HD_;
      k0 = *(const float4*)(kp + 0 * 16 * HD_);
      k1 = *(const float4*)(kp + 1 * 16 * HD_);
      k2 = *(const float4*)(kp + 2 * 16 * HD_);
      k3 = *(const float4*)(kp + 3 * 16 * HD_);
    }
    __syncthreads();

    f32x4 sacc[4];
    for (int n = 0; n < 4; ++n)
      for (int r = 0; r < 4; ++r) sacc[n][r] = 0.f;
#pragma unroll
    for (int n = 0; n < 4; ++n) {
      const unsigned short* krow_p = &Ks[(n * 16 + rowq) * KS_LD + koff];
      sacc[n] = __builtin_amdgcn_mfma_f32_16x16x32_bf16(qf0, *(const bf16x8*)(krow_p + 0 * 32), sacc[n], 0, 0, 0);
      sacc[n] = __builtin_amdgcn_mfma_f32_16x16x32_bf16(qf1, *(const bf16x8*)(krow_p + 1 * 32), sacc[n], 0, 0, 0);
      sacc[n] = __builtin_amdgcn_mfma_f32_16x16x32_bf16(qf2, *(const bf16x8*)(krow_p + 2 * 32), sacc[n], 0, 0, 0);
      sacc[n] = __builtin_amdgcn_mfma_f32_16x16x32_bf16(qf3, *(const bf16x8*)(krow_p + 3 * 32), sacc[n], 0, 0, 0);
    }

    float tmax[4] = {-3e38f, -3e38f, -3e38f, -3e38f};
    if (kt == qt) {
      for (int n = 0; n < 4; ++n) {
        int col = n * 16 + rowq;
        for (int r = 0; r < 4; ++r) {
          int row = w * 16 + lr0 + r;
          float x = (col <= row) ? sacc[n][r] : -1e30f;
          sacc[n][r] = x;
          tmax[r] = fmaxf(tmax[r], x);
        }
      }
    } else {
      for (int n = 0; n < 4; ++n)
        for (int r = 0; r < 4; ++r)
          tmax[r] = fmaxf(tmax[r], sacc[n][r]);
    }
    for (int off = 1; off < 16; off <<= 1)
      for (int r = 0; r < 4; ++r) tmax[r] = fmaxf(tmax[r], __shfl_xor(tmax[r], off));
    float alpha[4];
    for (int r = 0; r < 4; ++r) {
      float mn = fmaxf(m_r[r], tmax[r]);
      alpha[r] = __builtin_amdgcn_exp2f(m_r[r] - mn);
      m_r[r] = mn;
    }
    float rs[4] = {0.f, 0.f, 0.f, 0.f};
    for (int n = 0; n < 4; ++n)
      for (int r = 0; r < 4; ++r) {
        float p = __builtin_amdgcn_exp2f(sacc[n][r] - m_r[r]);
        sacc[n][r] = p;
        rs[r] += p;
      }
    for (int off = 1; off < 16; off <<= 1)
      for (int r = 0; r < 4; ++r) rs[r] += __shfl_xor(rs[r], off);
    for (int r = 0; r < 4; ++r) l_r[r] = l_r[r] * alpha[r] + rs[r];
    for (int nd = 0; nd < 8; ++nd)
      for (int r = 0; r < 4; ++r) oacc[nd][r] *= alpha[r];

    if (kt + 1 < nkt) {
      const unsigned short* vp = vptr + (size_t)(kt + 1) * 64;
      v0 = *(const float4*)(vp + 0 * 32 * S_);
      v1 = *(const float4*)(vp + 1 * 32 * S_);
      v2 = *(const float4*)(vp + 2 * 32 * S_);
      v3 = *(const float4*)(vp + 3 * 32 * S_);
    }

    unsigned short* pw = &Ps[w * 16 * PS_LD];
    for (int n = 0; n < 4; ++n)
      for (int r = 0; r < 4; ++r)
        pw[(lr0 + r) * PS_LD + n * 16 + rowq] = f2bf(sacc[n][r]);

#pragma unroll
    for (int t2 = 0; t2 < 2; ++t2) {
      bf16x8 pa = *(const bf16x8*)&pw[rowq * PS_LD + t2 * 32 + koff];
      for (int nd = 0; nd < 8; ++nd) {
        bf16x8 vb = *(const bf16x8*)&Vts[(nd * 16 + rowq) * VS_LD + t2 * 32 + koff];
        oacc[nd] = __builtin_amdgcn_mfma_f32_16x16x32_bf16(pa, vb, oacc[nd], 0, 0, 0);
      }
    }
  }

  float linv[4];
  for (int r = 0; r < 4; ++r) linv[r] = __builtin_amdgcn_rcpf(l_r[r]);
  for (int nd = 0; nd < 8; ++nd) {
    int col = h * HD_ + nd * 16 + rowq;
    for (int r = 0; r < 4; ++r) {
      int row = q0 + w * 16 + lr0 + r;
      Ob[(size_t)(b * S_ + row) * HID_ + col] = f2bf(oacc[nd][r] * linv[r]);
    }
  }
}

// ---------------- launcher ----------------
extern "C" void kernel_launch(void* const* d_in, const int* in_sizes, int n_in,
                              void* d_out, int out_size, void* d_ws, size_t ws_size,
                              hipStream_t stream) {
  (void)in_sizes; (void)n_in; (void)out_size; (void)ws_size;
  const float* hidden = (const float*)d_in[0];
  // d_in[1] = attention_mask (causal; reproduced analytically)
  const int* pos = (const int*)d_in[2];
  const float* Wq = (const float*)d_in[3];
  const float* Wk = (const float*)d_in[4];
  const float* Wv = (const float*)d_in[5];
  const float* Wo = (const float*)d_in[6];
  float* out = (float*)d_out;

  char* ws = (char*)d_ws;
  unsigned short* Xb   = (unsigned short*)(ws);               // 16 MB  (B,S,HID) bf16
  unsigned short* Wqb  = (unsigned short*)(ws + 16777216);    // 8 MB  Wq -- Wqb/Wkb/Wvb contiguous:
  unsigned short* Wkb  = (unsigned short*)(ws + 25165824);    // 8 MB  Wk -- one (6144,2048) QKV weight
  unsigned short* Wvb  = (unsigned short*)(ws + 33554432);    // 8 MB  Wv
  unsigned short* Wob  = (unsigned short*)(ws + 41943040);    // 8 MB
  unsigned short* Qb   = (unsigned short*)(ws + 50331648);    // 16 MB (B,NH,S,HD)
  unsigned short* Kb   = (unsigned short*)(ws + 67108864);    // 16 MB
  unsigned short* Vtmp = (unsigned short*)(ws + 83886080);    // 16 MB (B,S,HID)
  unsigned short* Vtb  = (unsigned short*)(ws + 100663296);   // 16 MB (B,NH,HD,S)
  unsigned short* Ob   = Xb;          // Xb dead after QKV GEMM
  float2* tbl          = (float2*)ws; // RoPE table also lives in dead Xb region (1 MB)

  cast_all<<<2048, 256, 0, stream>>>(hidden, Wq, Wk, Wv, Wo, Xb, Wqb, Wkb, Wvb, Wob);

  // fused QKV: C (4096 x 6144) = X (4096x2048) * Wqkv^T, 256x256 tiles
  dim3 gq(3 * HID_ / 256, (B_ * S_) / 256);  // (24, 16) = 384 blocks, 1/CU (128 KiB LDS)
  gemm_qkv<<<gq, 512, 0, stream>>>(Xb, Wqb, Qb, Kb, Vtmp);

  rope_table<<<(MAXTOK_ * 64) / 256, 256, 0, stream>>>(tbl);
  rope_apply<<<(B_ * NH_ * S_ * 64) / 256, 256, 0, stream>>>(Qb, Kb, pos, tbl);

  dim3 tg(S_ / 64, HD_ / 64, B_ * NH_);  // (32, 2, 32)
  transpose_v<<<tg, 256, 0, stream>>>(Vtmp, Vtb);

  dim3 ag(B_ * NH_, S_ / 64);  // bh fast, qt slow (descending inside kernel)
  attn_fused<<<ag, 256, 0, stream>>>(Qb, Kb, Vtb, Ob);

  dim3 go(HID_ / 128, (B_ * S_) / 128);  // (16, 32)
  gemm_out<<<go, 256, 0, stream>>>(Ob, Wob, out);
}

// Round 2
// 415.176 us; speedup vs baseline: 1.0671x; 1.0617x over previous
//
#include <hip/hip_runtime.h>

#define B_   2
#define S_   2048
#define HID_ 2048
#define NH_  16
#define HD_  128
#define MAXTOK_ 2048

typedef float  f32x4  __attribute__((ext_vector_type(4)));
typedef __bf16 bf16x8 __attribute__((ext_vector_type(8)));

__device__ __forceinline__ unsigned short f2bf(float f) {
  union { float fv; unsigned u; } v; v.fv = f;
  unsigned r = v.u + 0x7FFFu + ((v.u >> 16) & 1u);  // RNE
  return (unsigned short)(r >> 16);
}
__device__ __forceinline__ float bf2f(unsigned short h) {
  union { unsigned u; float fv; } v; v.u = ((unsigned)h) << 16;
  return v.fv;
}

// async global->LDS, 16B per lane (GEMM staging only; LDS dst must be contiguous)
__device__ __forceinline__ void gload16(const void* g, void* lds) {
  __builtin_amdgcn_global_load_lds(
      (const __attribute__((address_space(1))) void*)g,
      (__attribute__((address_space(3))) void*)lds, 16, 0, 0);
}

// ---------------- fused cast fp32 -> bf16 for hidden + 4 weights ----------------
#define H4_ (B_ * S_ * HID_ / 4)
#define W4_ (HID_ * HID_ / 4)
__global__ void cast_all(const float* __restrict__ h,  const float* __restrict__ wq,
                         const float* __restrict__ wk, const float* __restrict__ wv,
                         const float* __restrict__ wo,
                         unsigned short* __restrict__ xb,  unsigned short* __restrict__ wqb,
                         unsigned short* __restrict__ wkb, unsigned short* __restrict__ wvb,
                         unsigned short* __restrict__ wob) {
  const int total = H4_ + 4 * W4_;
  int i = blockIdx.x * blockDim.x + threadIdx.x;
  int stride = gridDim.x * blockDim.x;
  for (; i < total; i += stride) {
    const float* src; unsigned short* dst; int j;
    if (i < H4_) { src = h; dst = xb; j = i; }
    else {
      int k = i - H4_, wsel = k >> 20;  // W4_ = 2^20
      j = k & (W4_ - 1);
      src = (wsel == 0) ? wq : (wsel == 1) ? wk : (wsel == 2) ? wv : wo;
      dst = (wsel == 0) ? wqb : (wsel == 1) ? wkb : (wsel == 2) ? wvb : wob;
    }
    float4 v = ((const float4*)src)[j];
    ushort4 o;
    o.x = f2bf(v.x); o.y = f2bf(v.y); o.z = f2bf(v.z); o.w = f2bf(v.w);
    ((ushort4*)dst)[j] = o;
  }
}

// ---------------- fused QKV projection: 256x256 tile, BK=64, 8-phase schedule ----------------
// Round-1 postmortem fixes:
//  * REAL bank swizzle: rows are 128B (8 x 16B slots); bank = (row*32+slot*4)%32
//    -- row bits don't reach the bank index, only the slot does. Swizzle
//    slot' = slot ^ (row&7): rowq 0..7 cover all 8 slots, 8..15 repeat -> 2-way
//    (free, m136). Prior version XOR'd a single bit -> still ~8-way -> the
//    unchanged 1.26e7 SQ_LDS_BANK_CONFLICT.
//  * B tile fully register-resident (bfr[4][2]); phase order (0,0)(0,1)(1,1)(1,0)
//    eliminates the A-half re-read: LDS reads/tile 256KB -> 196KB (< MFMA time).
//  * Waits re-derived: vmcnt(4) end of ph1 (A1,A3 landed), vmcnt(2) at tile
//    boundary (next tile's B0-B3,A0,A2 landed). Never 0 in main loop.
// Staging issue order for tile t+1: B0,B1 | B2,B3 | A0,A2 | A1,A3.
#define QKV_STG(gp, lp, rb) gload16((gp) + (size_t)(rb) * 2048, (lp) + (rb) * 64)

#define QKV_LOADA(MH) do { \
  _Pragma("unroll") \
  for (int mi_ = 0; mi_ < 4; ++mi_) { \
    const char* rp_ = (const char*)Acur + (size_t)((wm + (MH) * 64 + mi_ * 16 + rowq) * 128); \
    af[mi_][0] = *(const bf16x8*)(rp_ + cb0); \
    af[mi_][1] = *(const bf16x8*)(rp_ + cb1); \
  } } while (0)

#define QKV_LOADB(NP) do { \
  _Pragma("unroll") \
  for (int ni_ = 0; ni_ < 2; ++ni_) { \
    const char* rp_ = (const char*)Bcur + (size_t)((wn + (NP) * 32 + ni_ * 16 + rowq) * 128); \
    bfr[(NP) * 2 + ni_][0] = *(const bf16x8*)(rp_ + cb0); \
    bfr[(NP) * 2 + ni_][1] = *(const bf16x8*)(rp_ + cb1); \
  } } while (0)

#define QKV_MFMA(MH, NP) do { \
  _Pragma("unroll") \
  for (int mi_ = 0; mi_ < 4; ++mi_) { \
    _Pragma("unroll") \
    for (int ni_ = 0; ni_ < 2; ++ni_) { \
      f32x4 c_ = acc[(MH) * 4 + mi_][(NP) * 2 + ni_]; \
      c_ = __builtin_amdgcn_mfma_f32_16x16x32_bf16(af[mi_][0], bfr[(NP) * 2 + ni_][0], c_, 0, 0, 0); \
      c_ = __builtin_amdgcn_mfma_f32_16x16x32_bf16(af[mi_][1], bfr[(NP) * 2 + ni_][1], c_, 0, 0, 0); \
      acc[(MH) * 4 + mi_][(NP) * 2 + ni_] = c_; \
    } } } while (0)

#define QKV_BAR    asm volatile("s_barrier" ::: "memory")
#define QKV_VMC4   asm volatile("s_waitcnt vmcnt(4)" ::: "memory")
#define QKV_VMC2   asm volatile("s_waitcnt vmcnt(2)" ::: "memory")
#define QKV_VMC0   asm volatile("s_waitcnt vmcnt(0)" ::: "memory")

__global__ __launch_bounds__(512, 2)
void gemm_qkv(const unsigned short* __restrict__ A,
              const unsigned short* __restrict__ Bw,
              unsigned short* __restrict__ Qb,
              unsigned short* __restrict__ Kb,
              unsigned short* __restrict__ Vtmp) {
  const int K = HID_;       // 2048
  const int NT = K / 64;    // 32 K-tiles
  __shared__ __align__(16) unsigned short As[2][256 * 64];
  __shared__ __align__(16) unsigned short Bs[2][256 * 64];

  const int tid = threadIdx.x, lane = tid & 63, w = tid >> 6;
  const int n0 = blockIdx.x * 256, m0 = blockIdx.y * 256;
  const int wm = (w >> 2) * 128, wn = (w & 3) * 64;
  const int rowq = lane & 15, klane = lane >> 4;
  // read-side swizzle: byte slot' = slot ^ (row&7); row&7 == rowq&7 (bases x16)
  const int sw  = (rowq & 7) << 4;
  const int cb0 = (klane * 16) ^ sw;          // ks=0 (slots 0..3)
  const int cb1 = ((klane + 4) * 16) ^ sw;    // ks=1 (slots 4..7)
  // staging: 512 threads x 16B = one 64-row block per call; linear LDS dst,
  // global source column pre-swizzled by the same involution
  const int srow = tid >> 3;                  // 0..63
  const int dc8  = (tid & 7) * 8;             // linear lds col (elements)
  const int scol = (((tid & 7) * 16) ^ ((srow & 7) << 4)) >> 1;  // global col (elems)

  const unsigned short* Ag = A  + (size_t)(m0 + srow) * K + scol;
  const unsigned short* Bg = Bw + (size_t)(n0 + srow) * K + scol;

  f32x4 acc[8][4];
#pragma unroll
  for (int i = 0; i < 8; ++i)
#pragma unroll
    for (int j = 0; j < 4; ++j)
#pragma unroll
      for (int r = 0; r < 4; ++r) acc[i][j][r] = 0.f;

  bf16x8 af[4][2], bfr[4][2];

  // prologue: stage tile 0 into buffer 0 (same issue order as steady state)
  {
    unsigned short* Al = (unsigned short*)&As[0][0] + srow * 64 + dc8;
    unsigned short* Bl = (unsigned short*)&Bs[0][0] + srow * 64 + dc8;
    QKV_STG(Bg, Bl, 0); QKV_STG(Bg, Bl, 64); QKV_STG(Bg, Bl, 128); QKV_STG(Bg, Bl, 192);
    QKV_STG(Ag, Al, 0); QKV_STG(Ag, Al, 128); QKV_STG(Ag, Al, 64); QKV_STG(Ag, Al, 192);
  }
  QKV_VMC2;   // oldest 6 (B0..B3, A0, A2) landed
  QKV_BAR;

  const unsigned short* Acur = &As[0][0];
  const unsigned short* Bcur = &Bs[0][0];
  unsigned short* Anx = (unsigned short*)&As[1][0];
  unsigned short* Bnx = (unsigned short*)&Bs[1][0];

  for (int t = 0; t < NT - 1; ++t) {
    const int kn = (t + 1) * 64;
    const unsigned short* Agk = Ag + kn;
    const unsigned short* Bgk = Bg + kn;
    unsigned short* Al = Anx + srow * 64 + dc8;
    unsigned short* Bl = Bnx + srow * 64 + dc8;

    // ph0: MFMA(0,0) -- read A-low + B-low, stage B0,B1
    QKV_LOADA(0); QKV_LOADB(0);
    QKV_STG(Bgk, Bl, 0); QKV_STG(Bgk, Bl, 64);
    QKV_BAR;
    __builtin_amdgcn_s_setprio(1); QKV_MFMA(0, 0); __builtin_amdgcn_s_setprio(0);
    QKV_BAR;
    // ph1: MFMA(0,1) -- read B-high (A-low resident), stage B2,B3; wait A1,A3
    QKV_LOADB(1);
    QKV_STG(Bgk, Bl, 128); QKV_STG(Bgk, Bl, 192);
    QKV_BAR;
    __builtin_amdgcn_s_setprio(1); QKV_MFMA(0, 1); __builtin_amdgcn_s_setprio(0);
    QKV_VMC4;   // outstanding: A1,A3,B0',B1',B2',B3' -> oldest 2 (A1,A3) land
    QKV_BAR;
    // ph2: MFMA(1,1) -- read A-high (B-high resident), stage A0,A2
    QKV_LOADA(1);
    QKV_STG(Agk, Al, 0); QKV_STG(Agk, Al, 128);
    QKV_BAR;
    __builtin_amdgcn_s_setprio(1); QKV_MFMA(1, 1); __builtin_amdgcn_s_setprio(0);
    QKV_BAR;
    // ph3: MFMA(1,0) -- no ds_reads (af=mh1, bfr[0..1] resident), stage A1,A3
    QKV_STG(Agk, Al, 64); QKV_STG(Agk, Al, 192);
    QKV_BAR;
    __builtin_amdgcn_s_setprio(1); QKV_MFMA(1, 0); __builtin_amdgcn_s_setprio(0);
    QKV_VMC2;   // oldest 6 of 8 (B0'..B3',A0',A2') landed for next ph0
    QKV_BAR;

    { const unsigned short* tp = Acur; Acur = Anx; Anx = (unsigned short*)tp; }
    { const unsigned short* tp = Bcur; Bcur = Bnx; Bnx = (unsigned short*)tp; }
  }

  // tail tile (no staging): drain A1,A3 before ph2's reads
  QKV_LOADA(0); QKV_LOADB(0);
  QKV_BAR;
  __builtin_amdgcn_s_setprio(1); QKV_MFMA(0, 0); __builtin_amdgcn_s_setprio(0);
  QKV_BAR;
  QKV_LOADB(1);
  QKV_BAR;
  __builtin_amdgcn_s_setprio(1); QKV_MFMA(0, 1); __builtin_amdgcn_s_setprio(0);
  QKV_VMC0;
  QKV_BAR;
  QKV_LOADA(1);
  QKV_BAR;
  __builtin_amdgcn_s_setprio(1); QKV_MFMA(1, 1); __builtin_amdgcn_s_setprio(0);
  QKV_BAR;
  __builtin_amdgcn_s_setprio(1); QKV_MFMA(1, 0); __builtin_amdgcn_s_setprio(0);

  // epilogue scatter (C/D layout: col=lane&15, row=(lane>>4)*4+r)
  const int lr0 = klane * 4;
#pragma unroll
  for (int mi = 0; mi < 8; ++mi)
#pragma unroll
    for (int ni = 0; ni < 4; ++ni)
#pragma unroll
      for (int r = 0; r < 4; ++r) {
        int r_ = m0 + wm + mi * 16 + lr0 + r;
        int c_ = n0 + wn + ni * 16 + rowq;
        float v = acc[mi][ni][r];
        int b = r_ >> 11, s = r_ & 2047;
        int proj = c_ >> 11, cin = c_ & 2047;
        if (proj == 2) {
          Vtmp[(size_t)(b * S_ + s) * HID_ + cin] = f2bf(v);
        } else {
          int hh = cin >> 7, d = cin & 127;
          unsigned short* dst = (proj == 0) ? Qb : Kb;
          dst[(((size_t)(b * NH_ + hh) * S_ + s) * HD_) + d] = f2bf(v);
        }
      }
}

// ---------------- output projection: 128x128 tile, BK=32, swizzled LDS ----------------
// Rows are 64B (4 x 16B slots); bank = (row*16+slot*4)%32 -> only row&1 and slot
// reach the bank. Swizzle slot' = slot ^ ((row>>1)&3): 16 rows -> 8 distinct
// bank-quads x 2 = 2-way (free). Source column pre-swizzled (rule #21).
__global__ __launch_bounds__(256, 2)
void gemm_out(const unsigned short* __restrict__ A,
              const unsigned short* __restrict__ Bw,
              float* __restrict__ Cout) {
  const int N = HID_, K = HID_;
  __shared__ __align__(16) unsigned short As[128 * 32];
  __shared__ __align__(16) unsigned short Bs[128 * 32];
  const int tid = threadIdx.x, lane = tid & 63, w = tid >> 6;
  const int n0 = blockIdx.x * 128, m0 = blockIdx.y * 128;
  const int wm = (w & 1) * 64, wn = (w >> 1) * 64;
  const int rowq = lane & 15;
  const int klane = lane >> 4;
  const int ko = ((klane ^ ((rowq >> 1) & 3)) * 8);  // swizzled read col (elems)
  const int lr0 = klane * 4;

  f32x4 acc[4][4];
  for (int i = 0; i < 4; ++i)
    for (int j = 0; j < 4; ++j)
      for (int r = 0; r < 4; ++r) acc[i][j][r] = 0.f;

  for (int k0 = 0; k0 < K; k0 += 32) {
    __syncthreads();
    for (int c = 0; c < 2; ++c) {
      int chunk = (w * 2 + c) * 64 + lane;
      int row = chunk >> 2, cc = chunk & 3;
      int sc = (cc ^ ((row >> 1) & 3)) * 8;  // pre-swizzled global col (elems)
      gload16(A + (size_t)(m0 + row) * K + k0 + sc, As + (w * 2 + c) * 512);
      gload16(Bw + (size_t)(n0 + row) * K + k0 + sc, Bs + (w * 2 + c) * 512);
    }
    __syncthreads();
    bf16x8 af[4], bfv[4];
    for (int i = 0; i < 4; ++i) {
      af[i]  = *(const bf16x8*)&As[(wm + i * 16 + rowq) * 32 + ko];
      bfv[i] = *(const bf16x8*)&Bs[(wn + i * 16 + rowq) * 32 + ko];
    }
    for (int mi = 0; mi < 4; ++mi)
      for (int ni = 0; ni < 4; ++ni)
        acc[mi][ni] = __builtin_amdgcn_mfma_f32_16x16x32_bf16(af[mi], bfv[ni], acc[mi][ni], 0, 0, 0);
  }

  for (int mi = 0; mi < 4; ++mi)
    for (int ni = 0; ni < 4; ++ni)
      for (int r = 0; r < 4; ++r) {
        int r_ = m0 + wm + mi * 16 + lr0 + r;
        int c_ = n0 + wn + ni * 16 + rowq;
        Cout[(size_t)r_ * N + c_] = acc[mi][ni][r];
      }
}

// ---------------- RoPE: table precompute + coalesced apply ----------------
__global__ void rope_table(float2* __restrict__ tbl) {
  int i = blockIdx.x * blockDim.x + threadIdx.x;  // p*64 + d
  if (i >= MAXTOK_ * 64) return;
  int p = i >> 6, d = i & 63;
  float f = __expf(-(float)d * (9.210340371976184f / 64.f));  // 10000^(-d/64)
  float sn, cs;
  __sincosf((float)p * f, &sn, &cs);
  tbl[i] = make_float2(cs, sn);
}

#define QSCALE_ 0.12751744f
__global__ __launch_bounds__(256)
void rope_apply(unsigned short* __restrict__ Qb, unsigned short* __restrict__ Kb,
                const int* __restrict__ pos_ids, const float2* __restrict__ tbl) {
  int i = blockIdx.x * blockDim.x + threadIdx.x;  // bhs*64 + d
  int d = i & 63, bhs = i >> 6;
  int s = bhs & (S_ - 1);
  int b = bhs >> 15;  // NH_*S_ = 32768
  int p = pos_ids[b * S_ + s];
  float2 cssn = tbl[p * 64 + d];
  size_t base = (size_t)bhs * HD_;
  {
    float x1 = bf2f(Qb[base + d]), x2 = bf2f(Qb[base + d + 64]);
    Qb[base + d]      = f2bf((x1 * cssn.x - x2 * cssn.y) * QSCALE_);
    Qb[base + d + 64] = f2bf((x2 * cssn.x + x1 * cssn.y) * QSCALE_);
  }
  {
    float x1 = bf2f(Kb[base + d]), x2 = bf2f(Kb[base + d + 64]);
    Kb[base + d]      = f2bf(x1 * cssn.x - x2 * cssn.y);
    Kb[base + d + 64] = f2bf(x2 * cssn.x + x1 * cssn.y);
  }
}

// ---------------- transpose V: (B,S,HID) bf16 -> (B,NH,HD,S) bf16 ----------------
__global__ __launch_bounds__(256)
void transpose_v(const unsigned short* __restrict__ Vin,
                 unsigned short* __restrict__ Vt) {
  __shared__ unsigned short t[64 * 66];
  const int s0 = blockIdx.x * 64, d0 = blockIdx.y * 64, bh = blockIdx.z;
  const int b = bh >> 4, h = bh & 15;
  for (int it = 0; it < 16; ++it) {
    int lin = it * 256 + threadIdx.x;
    int sl = lin >> 6, dl = lin & 63;
    t[sl * 66 + dl] = Vin[(size_t)(b * S_ + s0 + sl) * HID_ + h * HD_ + d0 + dl];
  }
  __syncthreads();
  for (int it = 0; it < 16; ++it) {
    int lin = it * 256 + threadIdx.x;
    int dl = lin >> 6, sl = lin & 63;
    Vt[((size_t)bh * HD_ + d0 + dl) * S_ + s0 + sl] = t[sl * 66 + dl];
  }
}

// ---------------- fused causal flash attention (v5) ----------------
#define KS_LD 136   // 64x128 K tile, padded (16B-aligned rows, 2-way bank aliasing)
#define VS_LD 72    // 128x64 V^T tile, padded
#define PS_LD 72    // 16x64 P tile per wave, padded (b128-aligned; Ps writes ~4-way)
__global__ __launch_bounds__(256, 2)
void attn_fused(const unsigned short* __restrict__ Qb,
                const unsigned short* __restrict__ Kb,
                const unsigned short* __restrict__ Vt,
                unsigned short* __restrict__ Ob) {
  __shared__ __align__(16) unsigned short Ks[64 * KS_LD];
  __shared__ __align__(16) unsigned short Vts[128 * VS_LD];
  __shared__ __align__(16) unsigned short Ps[4 * 16 * PS_LD];

  const int tid = threadIdx.x, lane = tid & 63, w = tid >> 6;
  const int bh = blockIdx.x;                    // fast dim: spreads heads across XCDs
  const int qt = (gridDim.y - 1) - blockIdx.y;  // descending: longest blocks first (LPT)
  const int q0 = qt * 64;
  const int b = bh >> 4, h = bh & 15;
  const int rowq = lane & 15;
  const int koff = (lane >> 4) * 8;
  const int lr0 = (lane >> 4) * 4;
  const size_t qkbase = (size_t)bh * (S_ * HD_);
  const size_t vbase  = (size_t)bh * (HD_ * S_);

  bf16x8 qf0, qf1, qf2, qf3;
  {
    const unsigned short* qrow = Qb + qkbase + (size_t)(q0 + w * 16 + rowq) * HD_;
    qf0 = *(const bf16x8*)(qrow + 0 * 32 + koff);
    qf1 = *(const bf16x8*)(qrow + 1 * 32 + koff);
    qf2 = *(const bf16x8*)(qrow + 2 * 32 + koff);
    qf3 = *(const bf16x8*)(qrow + 3 * 32 + koff);
  }

  const int krow = tid >> 4, kcol = (tid & 15) * 8;  // K: 16 rows/pass
  const int vrow = tid >> 3, vcol = (tid & 7) * 8;   // V^T: 32 rows/pass
  const unsigned short* kptr = Kb + qkbase + (size_t)krow * HD_ + kcol;
  const unsigned short* vptr = Vt + vbase + (size_t)vrow * S_ + vcol;

  f32x4 oacc[8];
  for (int i = 0; i < 8; ++i)
    for (int r = 0; r < 4; ++r) oacc[i][r] = 0.f;
  float m_r[4] = {-3e38f, -3e38f, -3e38f, -3e38f};
  float l_r[4] = {0.f, 0.f, 0.f, 0.f};

  const int nkt = qt + 1;

  float4 k0, k1, k2, k3, v0, v1, v2, v3;
  k0 = *(const float4*)(kptr + 0 * 16 * HD_);
  k1 = *(const float4*)(kptr + 1 * 16 * HD_);
  k2 = *(const float4*)(kptr + 2 * 16 * HD_);
  k3 = *(const float4*)(kptr + 3 * 16 * HD_);
  v0 = *(const float4*)(vptr + 0 * 32 * S_);
  v1 = *(const float4*)(vptr + 1 * 32 * S_);
  v2 = *(const float4*)(vptr + 2 * 32 * S_);
  v3 = *(const float4*)(vptr + 3 * 32 * S_);

  for (int kt = 0; kt < nkt; ++kt) {
    __syncthreads();  // previous tile's readers done
    *(float4*)&Ks[(krow + 0 * 16) * KS_LD + kcol] = k0;
    *(float4*)&Ks[(krow + 1 * 16) * KS_LD + kcol] = k1;
    *(float4*)&Ks[(krow + 2 * 16) * KS_LD + kcol] = k2;
    *(float4*)&Ks[(krow + 3 * 16) * KS_LD + kcol] = k3;
    *(float4*)&Vts[(vrow + 0 * 32) * VS_LD + vcol] = v0;
    *(float4*)&Vts[(vrow + 1 * 32) * VS_LD + vcol] = v1;
    *(float4*)&Vts[(vrow + 2 * 32) * VS_LD + vcol] = v2;
    *(float4*)&Vts[(vrow + 3 * 32) * VS_LD + vcol] = v3;
    if (kt + 1 < nkt) {
      const unsigned short* kp = kptr + (size_t)(kt + 1) * 64 * HD_;
      k0 = *(const float4*)(kp + 0 * 16 * HD_);
      k1 = *(const float4*)(kp + 1 * 16 * HD_);
      k2 = *(const float4*)(kp + 2 * 16 * HD_);
      k3 = *(const float4*)(kp + 3 * 16 * HD_);
    }
    __syncthreads();

    f32x4 sacc[4];
    for (int n = 0; n < 4; ++n)
      for (int r = 0; r < 4; ++r) sacc[n][r] = 0.f;
#pragma unroll
    for (int n = 0; n < 4; ++n) {
      const unsigned short* krow_p = &Ks[(n * 16 + rowq) * KS_LD + koff];
      sacc[n] = __builtin_amdgcn_mfma_f32_16x16x32_bf16(qf0, *(const bf16x8*)(krow_p + 0 * 32), sacc[n], 0, 0, 0);
      sacc[n] = __builtin_amdgcn_mfma_f32_16x16x32_bf16(qf1, *(const bf16x8*)(krow_p + 1 * 32), sacc[n], 0, 0, 0);
      sacc[n] = __builtin_amdgcn_mfma_f32_16x16x32_bf16(qf2, *(const bf16x8*)(krow_p + 2 * 32), sacc[n], 0, 0, 0);
      sacc[n] = __builtin_amdgcn_mfma_f32_16x16x32_bf16(qf3, *(const bf16x8*)(krow_p + 3 * 32), sacc[n], 0, 0, 0);
    }

    float tmax[4] = {-3e38f, -3e38f, -3e38f, -3e38f};
    if (kt == qt) {
      for (int n = 0; n < 4; ++n) {
        int col = n * 16 + rowq;
        for (int r = 0; r < 4; ++r) {
          int row = w * 16 + lr0 + r;
          float x = (col <= row) ? sacc[n][r] : -1e30f;
          sacc[n][r] = x;
          tmax[r] = fmaxf(tmax[r], x);
        }
      }
    } else {
      for (int n = 0; n < 4; ++n)
        for (int r = 0; r < 4; ++r)
          tmax[r] = fmaxf(tmax[r], sacc[n][r]);
    }
    for (int off = 1; off < 16; off <<= 1)
      for (int r = 0; r < 4; ++r) tmax[r] = fmaxf(tmax[r], __shfl_xor(tmax[r], off));
    float alpha[4];
    for (int r = 0; r < 4; ++r) {
      float mn = fmaxf(m_r[r], tmax[r]);
      alpha[r] = __builtin_amdgcn_exp2f(m_r[r] - mn);
      m_r[r] = mn;
    }
    float rs[4] = {0.f, 0.f, 0.f, 0.f};
    for (int n = 0; n < 4; ++n)
      for (int r = 0; r < 4; ++r) {
        float p = __builtin_amdgcn_exp2f(sacc[n][r] - m_r[r]);
        sacc[n][r] = p;
        rs[r] += p;
      }
    for (int off = 1; off < 16; off <<= 1)
      for (int r = 0; r < 4; ++r) rs[r] += __shfl_xor(rs[r], off);
    for (int r = 0; r < 4; ++r) l_r[r] = l_r[r] * alpha[r] + rs[r];
    for (int nd = 0; nd < 8; ++nd)
      for (int r = 0; r < 4; ++r) oacc[nd][r] *= alpha[r];

    if (kt + 1 < nkt) {
      const unsigned short* vp = vptr + (size_t)(kt + 1) * 64;
      v0 = *(const float4*)(vp + 0 * 32 * S_);
      v1 = *(const float4*)(vp + 1 * 32 * S_);
      v2 = *(const float4*)(vp + 2 * 32 * S_);
      v3 = *(const float4*)(vp + 3 * 32 * S_);
    }

    unsigned short* pw = &Ps[w * 16 * PS_LD];
    for (int n = 0; n < 4; ++n)
      for (int r = 0; r < 4; ++r)
        pw[(lr0 + r) * PS_LD + n * 16 + rowq] = f2bf(sacc[n][r]);

#pragma unroll
    for (int t2 = 0; t2 < 2; ++t2) {
      bf16x8 pa = *(const bf16x8*)&pw[rowq * PS_LD + t2 * 32 + koff];
      for (int nd = 0; nd < 8; ++nd) {
        bf16x8 vb = *(const bf16x8*)&Vts[(nd * 16 + rowq) * VS_LD + t2 * 32 + koff];
        oacc[nd] = __builtin_amdgcn_mfma_f32_16x16x32_bf16(pa, vb, oacc[nd], 0, 0, 0);
      }
    }
  }

  float linv[4];
  for (int r = 0; r < 4; ++r) linv[r] = __builtin_amdgcn_rcpf(l_r[r]);
  for (int nd = 0; nd < 8; ++nd) {
    int col = h * HD_ + nd * 16 + rowq;
    for (int r = 0; r < 4; ++r) {
      int row = q0 + w * 16 + lr0 + r;
      Ob[(size_t)(b * S_ + row) * HID_ + col] = f2bf(oacc[nd][r] * linv[r]);
    }
  }
}

// ---------------- launcher ----------------
extern "C" void kernel_launch(void* const* d_in, const int* in_sizes, int n_in,
                              void* d_out, int out_size, void* d_ws, size_t ws_size,
                              hipStream_t stream) {
  (void)in_sizes; (void)n_in; (void)out_size; (void)ws_size;
  const float* hidden = (const float*)d_in[0];
  // d_in[1] = attention_mask (causal; reproduced analytically)
  const int* pos = (const int*)d_in[2];
  const float* Wq = (const float*)d_in[3];
  const float* Wk = (const float*)d_in[4];
  const float* Wv = (const float*)d_in[5];
  const float* Wo = (const float*)d_in[6];
  float* out = (float*)d_out;

  char* ws = (char*)d_ws;
  unsigned short* Xb   = (unsigned short*)(ws);               // 16 MB  (B,S,HID) bf16
  unsigned short* Wqb  = (unsigned short*)(ws + 16777216);    // 8 MB  Wq -- Wqb/Wkb/Wvb contiguous:
  unsigned short* Wkb  = (unsigned short*)(ws + 25165824);    // 8 MB  Wk -- one (6144,2048) QKV weight
  unsigned short* Wvb  = (unsigned short*)(ws + 33554432);    // 8 MB  Wv
  unsigned short* Wob  = (unsigned short*)(ws + 41943040);    // 8 MB
  unsigned short* Qb   = (unsigned short*)(ws + 50331648);    // 16 MB (B,NH,S,HD)
  unsigned short* Kb   = (unsigned short*)(ws + 67108864);    // 16 MB
  unsigned short* Vtmp = (unsigned short*)(ws + 83886080);    // 16 MB (B,S,HID)
  unsigned short* Vtb  = (unsigned short*)(ws + 100663296);   // 16 MB (B,NH,HD,S)
  unsigned short* Ob   = Xb;          // Xb dead after QKV GEMM
  float2* tbl          = (float2*)ws; // RoPE table also lives in dead Xb region (1 MB)

  cast_all<<<2048, 256, 0, stream>>>(hidden, Wq, Wk, Wv, Wo, Xb, Wqb, Wkb, Wvb, Wob);

  // fused QKV: C (4096 x 6144) = X (4096x2048) * Wqkv^T, 256x256 tiles
  dim3 gq(3 * HID_ / 256, (B_ * S_) / 256);  // (24, 16) = 384 blocks, 1/CU (128 KiB LDS)
  gemm_qkv<<<gq, 512, 0, stream>>>(Xb, Wqb, Qb, Kb, Vtmp);

  rope_table<<<(MAXTOK_ * 64) / 256, 256, 0, stream>>>(tbl);
  rope_apply<<<(B_ * NH_ * S_ * 64) / 256, 256, 0, stream>>>(Qb, Kb, pos, tbl);

  dim3 tg(S_ / 64, HD_ / 64, B_ * NH_);  // (32, 2, 32)
  transpose_v<<<tg, 256, 0, stream>>>(Vtmp, Vtb);

  dim3 ag(B_ * NH_, S_ / 64);  // bh fast, qt slow (descending inside kernel)
  attn_fused<<<ag, 256, 0, stream>>>(Qb, Kb, Vtb, Ob);

  dim3 go(HID_ / 128, (B_ * S_) / 128);  // (16, 32)
  gemm_out<<<go, 256, 0, stream>>>(Ob, Wob, out);
}

// Round 3
// 399.945 us; speedup vs baseline: 1.1077x; 1.0381x over previous
//
#include <hip/hip_runtime.h>

#define B_   2
#define S_   2048
#define HID_ 2048
#define NH_  16
#define HD_  128
#define MAXTOK_ 2048

typedef float  f32x4  __attribute__((ext_vector_type(4)));
typedef __bf16 bf16x8 __attribute__((ext_vector_type(8)));

__device__ __forceinline__ unsigned short f2bf(float f) {
  union { float fv; unsigned u; } v; v.fv = f;
  unsigned r = v.u + 0x7FFFu + ((v.u >> 16) & 1u);  // RNE
  return (unsigned short)(r >> 16);
}
__device__ __forceinline__ float bf2f(unsigned short h) {
  union { unsigned u; float fv; } v; v.u = ((unsigned)h) << 16;
  return v.fv;
}

// async global->LDS, 16B per lane (GEMM staging only; LDS dst must be contiguous)
__device__ __forceinline__ void gload16(const void* g, void* lds) {
  __builtin_amdgcn_global_load_lds(
      (const __attribute__((address_space(1))) void*)g,
      (__attribute__((address_space(3))) void*)lds, 16, 0, 0);
}

// ---------------- fused cast fp32 -> bf16 for hidden + 4 weights ----------------
#define H4_ (B_ * S_ * HID_ / 4)
#define W4_ (HID_ * HID_ / 4)
__global__ void cast_all(const float* __restrict__ h,  const float* __restrict__ wq,
                         const float* __restrict__ wk, const float* __restrict__ wv,
                         const float* __restrict__ wo,
                         unsigned short* __restrict__ xb,  unsigned short* __restrict__ wqb,
                         unsigned short* __restrict__ wkb, unsigned short* __restrict__ wvb,
                         unsigned short* __restrict__ wob) {
  const int total = H4_ + 4 * W4_;
  int i = blockIdx.x * blockDim.x + threadIdx.x;
  int stride = gridDim.x * blockDim.x;
  for (; i < total; i += stride) {
    const float* src; unsigned short* dst; int j;
    if (i < H4_) { src = h; dst = xb; j = i; }
    else {
      int k = i - H4_, wsel = k >> 20;  // W4_ = 2^20
      j = k & (W4_ - 1);
      src = (wsel == 0) ? wq : (wsel == 1) ? wk : (wsel == 2) ? wv : wo;
      dst = (wsel == 0) ? wqb : (wsel == 1) ? wkb : (wsel == 2) ? wvb : wob;
    }
    float4 v = ((const float4*)src)[j];
    ushort4 o;
    o.x = f2bf(v.x); o.y = f2bf(v.y); o.z = f2bf(v.z); o.w = f2bf(v.w);
    ((ushort4*)dst)[j] = o;
  }
}

// ---------------- fused QKV projection: 256x192 tile, BK=64, 4-phase/K-tile ----------------
// Round-2 postmortem: conflicts=0 but flat time -> latency/quantization-bound.
// Fixes:
//  * BN 256->192: grid (32,16) = 512 blocks = EXACTLY 2 rounds at 1 block/CU
//    (was 384 = 1.5 rounds = hard 75% ceiling).
//  * Phases iterate m-quarters q=0..3 (12 MFMA each); B tile fully
//    register-resident (bfr[3][2], loaded once per K-tile at ph0).
//    Need-by sets are clean: ph0 needs {B0,B1,B2,A0,A2}, ph2 needs {A1,A3}.
//  * Staging order B0,B1 | B2,A0 | A2,A1 | A3 makes need-sets = oldest-k:
//    vmcnt(4) end-ph1 (A1,A3 of current tile landed, slack 2-3 phases),
//    vmcnt(2) end-ph3 (next tile's first 5 landed, slack 3-4 phases).
//    Never 0 in the main loop. 7 loads/tile (was 8).
//  * Swizzle from round 2 kept verbatim (verified: SQ_LDS_BANK_CONFLICT = 0):
//    byte slot' = slot ^ (row&7), linear LDS dst + pre-swizzled global col.
#define QKV_STG(gp, lp, rb) gload16((gp) + (size_t)(rb) * 2048, (lp) + (rb) * 64)

#define QKV_LOADA(Q) do { \
  _Pragma("unroll") \
  for (int mi_ = 0; mi_ < 2; ++mi_) { \
    const char* rp_ = (const char*)Acur + (size_t)((wm + (Q) * 32 + mi_ * 16 + rowq) * 128); \
    af[mi_][0] = *(const bf16x8*)(rp_ + cb0); \
    af[mi_][1] = *(const bf16x8*)(rp_ + cb1); \
  } } while (0)

#define QKV_LOADB() do { \
  _Pragma("unroll") \
  for (int ni_ = 0; ni_ < 3; ++ni_) { \
    const char* rp_ = (const char*)Bcur + (size_t)((wn + ni_ * 16 + rowq) * 128); \
    bfr[ni_][0] = *(const bf16x8*)(rp_ + cb0); \
    bfr[ni_][1] = *(const bf16x8*)(rp_ + cb1); \
  } } while (0)

#define QKV_MFMA(Q) do { \
  _Pragma("unroll") \
  for (int mi_ = 0; mi_ < 2; ++mi_) { \
    _Pragma("unroll") \
    for (int ni_ = 0; ni_ < 3; ++ni_) { \
      f32x4 c_ = acc[(Q) * 2 + mi_][ni_]; \
      c_ = __builtin_amdgcn_mfma_f32_16x16x32_bf16(af[mi_][0], bfr[ni_][0], c_, 0, 0, 0); \
      c_ = __builtin_amdgcn_mfma_f32_16x16x32_bf16(af[mi_][1], bfr[ni_][1], c_, 0, 0, 0); \
      acc[(Q) * 2 + mi_][ni_] = c_; \
    } } } while (0)

#define QKV_BAR    asm volatile("s_barrier" ::: "memory")
#define QKV_VMC4   asm volatile("s_waitcnt vmcnt(4)" ::: "memory")
#define QKV_VMC2   asm volatile("s_waitcnt vmcnt(2)" ::: "memory")
#define QKV_VMC0   asm volatile("s_waitcnt vmcnt(0)" ::: "memory")

__global__ __launch_bounds__(512, 2)
void gemm_qkv(const unsigned short* __restrict__ A,
              const unsigned short* __restrict__ Bw,
              unsigned short* __restrict__ Qb,
              unsigned short* __restrict__ Kb,
              unsigned short* __restrict__ Vtmp) {
  const int K = HID_;       // 2048
  const int NT = K / 64;    // 32 K-tiles
  __shared__ __align__(16) unsigned short As[2][256 * 64];
  __shared__ __align__(16) unsigned short Bs[2][192 * 64];

  const int tid = threadIdx.x, lane = tid & 63, w = tid >> 6;
  const int n0 = blockIdx.x * 192, m0 = blockIdx.y * 256;
  const int wm = (w >> 2) * 128, wn = (w & 3) * 48;
  const int rowq = lane & 15, klane = lane >> 4;
  // read-side swizzle: byte slot' = slot ^ (row&7); row&7 == rowq&7 (bases x16/x32/x48)
  const int sw  = (rowq & 7) << 4;
  const int cb0 = (klane * 16) ^ sw;          // ks=0 (slots 0..3)
  const int cb1 = ((klane + 4) * 16) ^ sw;    // ks=1 (slots 4..7)
  // staging: 512 threads x 16B = one 64-row block per call; linear LDS dst,
  // global source column pre-swizzled by the same involution
  const int srow = tid >> 3;                  // 0..63
  const int dc8  = (tid & 7) * 8;             // linear lds col (elements)
  const int scol = (((tid & 7) * 16) ^ ((srow & 7) << 4)) >> 1;  // global col (elems)

  const unsigned short* Ag = A  + (size_t)(m0 + srow) * K + scol;
  const unsigned short* Bg = Bw + (size_t)(n0 + srow) * K + scol;

  f32x4 acc[8][3];
#pragma unroll
  for (int i = 0; i < 8; ++i)
#pragma unroll
    for (int j = 0; j < 3; ++j)
#pragma unroll
      for (int r = 0; r < 4; ++r) acc[i][j][r] = 0.f;

  bf16x8 af[2][2], bfr[3][2];

  // prologue: stage tile 0 into buffer 0 (same issue order as steady state)
  {
    unsigned short* Al = (unsigned short*)&As[0][0] + srow * 64 + dc8;
    unsigned short* Bl = (unsigned short*)&Bs[0][0] + srow * 64 + dc8;
    QKV_STG(Bg, Bl, 0); QKV_STG(Bg, Bl, 64); QKV_STG(Bg, Bl, 128);
    QKV_STG(Ag, Al, 0); QKV_STG(Ag, Al, 128);
    QKV_STG(Ag, Al, 64); QKV_STG(Ag, Al, 192);
  }
  QKV_VMC2;   // oldest 5 (B0,B1,B2,A0,A2) landed
  QKV_BAR;

  const unsigned short* Acur = &As[0][0];
  const unsigned short* Bcur = &Bs[0][0];
  unsigned short* Anx = (unsigned short*)&As[1][0];
  unsigned short* Bnx = (unsigned short*)&Bs[1][0];

  for (int t = 0; t < NT - 1; ++t) {
    const int kn = (t + 1) * 64;
    const unsigned short* Agk = Ag + kn;
    const unsigned short* Bgk = Bg + kn;
    unsigned short* Al = Anx + srow * 64 + dc8;
    unsigned short* Bl = Bnx + srow * 64 + dc8;

    // ph0: q0 -- read A rows [wm, wm+32) + all B frags; stage B0',B1'
    QKV_LOADA(0); QKV_LOADB();
    QKV_STG(Bgk, Bl, 0); QKV_STG(Bgk, Bl, 64);
    QKV_BAR;
    __builtin_amdgcn_s_setprio(1); QKV_MFMA(0); __builtin_amdgcn_s_setprio(0);
    QKV_BAR;
    // ph1: q1 -- read A rows [wm+32, wm+64); stage B2',A0'; wait A1,A3 (cur)
    QKV_LOADA(1);
    QKV_STG(Bgk, Bl, 128); QKV_STG(Agk, Al, 0);
    QKV_BAR;
    __builtin_amdgcn_s_setprio(1); QKV_MFMA(1); __builtin_amdgcn_s_setprio(0);
    QKV_VMC4;   // outstanding: A1,A3,B0',B1',B2',A0' -> oldest 2 (A1,A3) land
    QKV_BAR;
    // ph2: q2 -- read A rows [wm+64, wm+96); stage A2',A1'
    QKV_LOADA(2);
    QKV_STG(Agk, Al, 128); QKV_STG(Agk, Al, 64);
    QKV_BAR;
    __builtin_amdgcn_s_setprio(1); QKV_MFMA(2); __builtin_amdgcn_s_setprio(0);
    QKV_BAR;
    // ph3: q3 -- read A rows [wm+96, wm+128); stage A3'; wait next tile's first 5
    QKV_LOADA(3);
    QKV_STG(Agk, Al, 192);
    QKV_BAR;
    __builtin_amdgcn_s_setprio(1); QKV_MFMA(3); __builtin_amdgcn_s_setprio(0);
    QKV_VMC2;   // oldest 5 of 7 (B0',B1',B2',A0',A2') landed for next ph0
    QKV_BAR;

    { const unsigned short* tp = Acur; Acur = Anx; Anx = (unsigned short*)tp; }
    { const unsigned short* tp = Bcur; Bcur = Bnx; Bnx = (unsigned short*)tp; }
  }

  // tail tile (no staging): outstanding at entry = A1,A3 of this tile
  QKV_LOADA(0); QKV_LOADB();
  QKV_BAR;
  __builtin_amdgcn_s_setprio(1); QKV_MFMA(0); __builtin_amdgcn_s_setprio(0);
  QKV_BAR;
  QKV_LOADA(1);
  QKV_BAR;
  __builtin_amdgcn_s_setprio(1); QKV_MFMA(1); __builtin_amdgcn_s_setprio(0);
  QKV_VMC0;   // drain A1,A3 before ph2's reads
  QKV_BAR;
  QKV_LOADA(2);
  QKV_BAR;
  __builtin_amdgcn_s_setprio(1); QKV_MFMA(2); __builtin_amdgcn_s_setprio(0);
  QKV_BAR;
  QKV_LOADA(3);
  __builtin_amdgcn_s_setprio(1); QKV_MFMA(3); __builtin_amdgcn_s_setprio(0);

  // epilogue scatter (C/D layout: col=lane&15, row=(lane>>4)*4+r)
  const int lr0 = klane * 4;
#pragma unroll
  for (int mi = 0; mi < 8; ++mi)
#pragma unroll
    for (int ni = 0; ni < 3; ++ni)
#pragma unroll
      for (int r = 0; r < 4; ++r) {
        int r_ = m0 + wm + mi * 16 + lr0 + r;
        int c_ = n0 + wn + ni * 16 + rowq;
        float v = acc[mi][ni][r];
        int b = r_ >> 11, s = r_ & 2047;
        int proj = c_ >> 11, cin = c_ & 2047;
        if (proj == 2) {
          Vtmp[(size_t)(b * S_ + s) * HID_ + cin] = f2bf(v);
        } else {
          int hh = cin >> 7, d = cin & 127;
          unsigned short* dst = (proj == 0) ? Qb : Kb;
          dst[(((size_t)(b * NH_ + hh) * S_ + s) * HD_) + d] = f2bf(v);
        }
      }
}

// ---------------- output projection: 128x128 tile, BK=32, swizzled LDS ----------------
// Rows are 64B (4 x 16B slots); swizzle slot' = slot ^ ((row>>1)&3) -> 2-way (free).
// Source column pre-swizzled (rule #21). Verified r2: conflicts ~0, time improved.
__global__ __launch_bounds__(256, 2)
void gemm_out(const unsigned short* __restrict__ A,
              const unsigned short* __restrict__ Bw,
              float* __restrict__ Cout) {
  const int N = HID_, K = HID_;
  __shared__ __align__(16) unsigned short As[128 * 32];
  __shared__ __align__(16) unsigned short Bs[128 * 32];
  const int tid = threadIdx.x, lane = tid & 63, w = tid >> 6;
  const int n0 = blockIdx.x * 128, m0 = blockIdx.y * 128;
  const int wm = (w & 1) * 64, wn = (w >> 1) * 64;
  const int rowq = lane & 15;
  const int klane = lane >> 4;
  const int ko = ((klane ^ ((rowq >> 1) & 3)) * 8);  // swizzled read col (elems)
  const int lr0 = klane * 4;

  f32x4 acc[4][4];
  for (int i = 0; i < 4; ++i)
    for (int j = 0; j < 4; ++j)
      for (int r = 0; r < 4; ++r) acc[i][j][r] = 0.f;

  for (int k0 = 0; k0 < K; k0 += 32) {
    __syncthreads();
    for (int c = 0; c < 2; ++c) {
      int chunk = (w * 2 + c) * 64 + lane;
      int row = chunk >> 2, cc = chunk & 3;
      int sc = (cc ^ ((row >> 1) & 3)) * 8;  // pre-swizzled global col (elems)
      gload16(A + (size_t)(m0 + row) * K + k0 + sc, As + (w * 2 + c) * 512);
      gload16(Bw + (size_t)(n0 + row) * K + k0 + sc, Bs + (w * 2 + c) * 512);
    }
    __syncthreads();
    bf16x8 af[4], bfv[4];
    for (int i = 0; i < 4; ++i) {
      af[i]  = *(const bf16x8*)&As[(wm + i * 16 + rowq) * 32 + ko];
      bfv[i] = *(const bf16x8*)&Bs[(wn + i * 16 + rowq) * 32 + ko];
    }
    for (int mi = 0; mi < 4; ++mi)
      for (int ni = 0; ni < 4; ++ni)
        acc[mi][ni] = __builtin_amdgcn_mfma_f32_16x16x32_bf16(af[mi], bfv[ni], acc[mi][ni], 0, 0, 0);
  }

  for (int mi = 0; mi < 4; ++mi)
    for (int ni = 0; ni < 4; ++ni)
      for (int r = 0; r < 4; ++r) {
        int r_ = m0 + wm + mi * 16 + lr0 + r;
        int c_ = n0 + wn + ni * 16 + rowq;
        Cout[(size_t)r_ * N + c_] = acc[mi][ni][r];
      }
}

// ---------------- RoPE: table precompute + coalesced apply ----------------
__global__ void rope_table(float2* __restrict__ tbl) {
  int i = blockIdx.x * blockDim.x + threadIdx.x;  // p*64 + d
  if (i >= MAXTOK_ * 64) return;
  int p = i >> 6, d = i & 63;
  float f = __expf(-(float)d * (9.210340371976184f / 64.f));  // 10000^(-d/64)
  float sn, cs;
  __sincosf((float)p * f, &sn, &cs);
  tbl[i] = make_float2(cs, sn);
}

#define QSCALE_ 0.12751744f
__global__ __launch_bounds__(256)
void rope_apply(unsigned short* __restrict__ Qb, unsigned short* __restrict__ Kb,
                const int* __restrict__ pos_ids, const float2* __restrict__ tbl) {
  int i = blockIdx.x * blockDim.x + threadIdx.x;  // bhs*64 + d
  int d = i & 63, bhs = i >> 6;
  int s = bhs & (S_ - 1);
  int b = bhs >> 15;  // NH_*S_ = 32768
  int p = pos_ids[b * S_ + s];
  float2 cssn = tbl[p * 64 + d];
  size_t base = (size_t)bhs * HD_;
  {
    float x1 = bf2f(Qb[base + d]), x2 = bf2f(Qb[base + d + 64]);
    Qb[base + d]      = f2bf((x1 * cssn.x - x2 * cssn.y) * QSCALE_);
    Qb[base + d + 64] = f2bf((x2 * cssn.x + x1 * cssn.y) * QSCALE_);
  }
  {
    float x1 = bf2f(Kb[base + d]), x2 = bf2f(Kb[base + d + 64]);
    Kb[base + d]      = f2bf(x1 * cssn.x - x2 * cssn.y);
    Kb[base + d + 64] = f2bf(x2 * cssn.x + x1 * cssn.y);
  }
}

// ---------------- transpose V: (B,S,HID) bf16 -> (B,NH,HD,S) bf16 ----------------
__global__ __launch_bounds__(256)
void transpose_v(const unsigned short* __restrict__ Vin,
                 unsigned short* __restrict__ Vt) {
  __shared__ unsigned short t[64 * 66];
  const int s0 = blockIdx.x * 64, d0 = blockIdx.y * 64, bh = blockIdx.z;
  const int b = bh >> 4, h = bh & 15;
  for (int it = 0; it < 16; ++it) {
    int lin = it * 256 + threadIdx.x;
    int sl = lin >> 6, dl = lin & 63;
    t[sl * 66 + dl] = Vin[(size_t)(b * S_ + s0 + sl) * HID_ + h * HD_ + d0 + dl];
  }
  __syncthreads();
  for (int it = 0; it < 16; ++it) {
    int lin = it * 256 + threadIdx.x;
    int dl = lin >> 6, sl = lin & 63;
    Vt[((size_t)bh * HD_ + d0 + dl) * S_ + s0 + sl] = t[sl * 66 + dl];
  }
}

// ---------------- fused causal flash attention (v5) ----------------
#define KS_LD 136   // 64x128 K tile, padded (16B-aligned rows, 2-way bank aliasing)
#define VS_LD 72    // 128x64 V^T tile, padded
#define PS_LD 72    // 16x64 P tile per wave, padded (b128-aligned; Ps writes ~4-way)
__global__ __launch_bounds__(256, 2)
void attn_fused(const unsigned short* __restrict__ Qb,
                const unsigned short* __restrict__ Kb,
                const unsigned short* __restrict__ Vt,
                unsigned short* __restrict__ Ob) {
  __shared__ __align__(16) unsigned short Ks[64 * KS_LD];
  __shared__ __align__(16) unsigned short Vts[128 * VS_LD];
  __shared__ __align__(16) unsigned short Ps[4 * 16 * PS_LD];

  const int tid = threadIdx.x, lane = tid & 63, w = tid >> 6;
  const int bh = blockIdx.x;                    // fast dim: spreads heads across XCDs
  const int qt = (gridDim.y - 1) - blockIdx.y;  // descending: longest blocks first (LPT)
  const int q0 = qt * 64;
  const int b = bh >> 4, h = bh & 15;
  const int rowq = lane & 15;
  const int koff = (lane >> 4) * 8;
  const int lr0 = (lane >> 4) * 4;
  const size_t qkbase = (size_t)bh * (S_ * HD_);
  const size_t vbase  = (size_t)bh * (HD_ * S_);

  bf16x8 qf0, qf1, qf2, qf3;
  {
    const unsigned short* qrow = Qb + qkbase + (size_t)(q0 + w * 16 + rowq) * HD_;
    qf0 = *(const bf16x8*)(qrow + 0 * 32 + koff);
    qf1 = *(const bf16x8*)(qrow + 1 * 32 + koff);
    qf2 = *(const bf16x8*)(qrow + 2 * 32 + koff);
    qf3 = *(const bf16x8*)(qrow + 3 * 32 + koff);
  }

  const int krow = tid >> 4, kcol = (tid & 15) * 8;  // K: 16 rows/pass
  const int vrow = tid >> 3, vcol = (tid & 7) * 8;   // V^T: 32 rows/pass
  const unsigned short* kptr = Kb + qkbase + (size_t)krow * HD_ + kcol;
  const unsigned short* vptr = Vt + vbase + (size_t)vrow * S_ + vcol;

  f32x4 oacc[8];
  for (int i = 0; i < 8; ++i)
    for (int r = 0; r < 4; ++r) oacc[i][r] = 0.f;
  float m_r[4] = {-3e38f, -3e38f, -3e38f, -3e38f};
  float l_r[4] = {0.f, 0.f, 0.f, 0.f};

  const int nkt = qt + 1;

  float4 k0, k1, k2, k3, v0, v1, v2, v3;
  k0 = *(const float4*)(kptr + 0 * 16 * HD_);
  k1 = *(const float4*)(kptr + 1 * 16 * HD_);
  k2 = *(const float4*)(kptr + 2 * 16 * HD_);
  k3 = *(const float4*)(kptr + 3 * 16 * HD_);
  v0 = *(const float4*)(vptr + 0 * 32 * S_);
  v1 = *(const float4*)(vptr + 1 * 32 * S_);
  v2 = *(const float4*)(vptr + 2 * 32 * S_);
  v3 = *(const float4*)(vptr + 3 * 32 * S_);

  for (int kt = 0; kt < nkt; ++kt) {
    __syncthreads();  // previous tile's readers done
    *(float4*)&Ks[(krow + 0 * 16) * KS_LD + kcol] = k0;
    *(float4*)&Ks[(krow + 1 * 16) * KS_LD + kcol] = k1;
    *(float4*)&Ks[(krow + 2 * 16) * KS_LD + kcol] = k2;
    *(float4*)&Ks[(krow + 3 * 16) * KS_LD + kcol] = k3;
    *(float4*)&Vts[(vrow + 0 * 32) * VS_LD + vcol] = v0;
    *(float4*)&Vts[(vrow + 1 * 32) * VS_LD + vcol] = v1;
    *(float4*)&Vts[(vrow + 2 * 32) * VS_LD + vcol] = v2;
    *(float4*)&Vts[(vrow + 3 * 32) * VS_LD + vcol] = v3;
    if (kt + 1 < nkt) {
      const unsigned short* kp = kptr + (size_t)(kt + 1) * 64 * HD_;
      k0 = *(const float4*)(kp + 0 * 16 * HD_);
      k1 = *(const float4*)(kp + 1 * 16 * HD_);
      k2 = *(const float4*)(kp + 2 * 16 * HD_);
      k3 = *(const float4*)(kp + 3 * 16 * HD_);
    }
    __syncthreads();

    f32x4 sacc[4];
    for (int n = 0; n < 4; ++n)
      for (int r = 0; r < 4; ++r) sacc[n][r] = 0.f;
#pragma unroll
    for (int n = 0; n < 4; ++n) {
      const unsigned short* krow_p = &Ks[(n * 16 + rowq) * KS_LD + koff];
      sacc[n] = __builtin_amdgcn_mfma_f32_16x16x32_bf16(qf0, *(const bf16x8*)(krow_p + 0 * 32), sacc[n], 0, 0, 0);
      sacc[n] = __builtin_amdgcn_mfma_f32_16x16x32_bf16(qf1, *(const bf16x8*)(krow_p + 1 * 32), sacc[n], 0, 0, 0);
      sacc[n] = __builtin_amdgcn_mfma_f32_16x16x32_bf16(qf2, *(const bf16x8*)(krow_p + 2 * 32), sacc[n], 0, 0, 0);
      sacc[n] = __builtin_amdgcn_mfma_f32_16x16x32_bf16(qf3, *(const bf16x8*)(krow_p + 3 * 32), sacc[n], 0, 0, 0);
    }

    float tmax[4] = {-3e38f, -3e38f, -3e38f, -3e38f};
    if (kt == qt) {
      for (int n = 0; n < 4; ++n) {
        int col = n * 16 + rowq;
        for (int r = 0; r < 4; ++r) {
          int row = w * 16 + lr0 + r;
          float x = (col <= row) ? sacc[n][r] : -1e30f;
          sacc[n][r] = x;
          tmax[r] = fmaxf(tmax[r], x);
        }
      }
    } else {
      for (int n = 0; n < 4; ++n)
        for (int r = 0; r < 4; ++r)
          tmax[r] = fmaxf(tmax[r], sacc[n][r]);
    }
    for (int off = 1; off < 16; off <<= 1)
      for (int r = 0; r < 4; ++r) tmax[r] = fmaxf(tmax[r], __shfl_xor(tmax[r], off));
    float alpha[4];
    for (int r = 0; r < 4; ++r) {
      float mn = fmaxf(m_r[r], tmax[r]);
      alpha[r] = __builtin_amdgcn_exp2f(m_r[r] - mn);
      m_r[r] = mn;
    }
    float rs[4] = {0.f, 0.f, 0.f, 0.f};
    for (int n = 0; n < 4; ++n)
      for (int r = 0; r < 4; ++r) {
        float p = __builtin_amdgcn_exp2f(sacc[n][r] - m_r[r]);
        sacc[n][r] = p;
        rs[r] += p;
      }
    for (int off = 1; off < 16; off <<= 1)
      for (int r = 0; r < 4; ++r) rs[r] += __shfl_xor(rs[r], off);
    for (int r = 0; r < 4; ++r) l_r[r] = l_r[r] * alpha[r] + rs[r];
    for (int nd = 0; nd < 8; ++nd)
      for (int r = 0; r < 4; ++r) oacc[nd][r] *= alpha[r];

    if (kt + 1 < nkt) {
      const unsigned short* vp = vptr + (size_t)(kt + 1) * 64;
      v0 = *(const float4*)(vp + 0 * 32 * S_);
      v1 = *(const float4*)(vp + 1 * 32 * S_);
      v2 = *(const float4*)(vp + 2 * 32 * S_);
      v3 = *(const float4*)(vp + 3 * 32 * S_);
    }

    unsigned short* pw = &Ps[w * 16 * PS_LD];
    for (int n = 0; n < 4; ++n)
      for (int r = 0; r < 4; ++r)
        pw[(lr0 + r) * PS_LD + n * 16 + rowq] = f2bf(sacc[n][r]);

#pragma unroll
    for (int t2 = 0; t2 < 2; ++t2) {
      bf16x8 pa = *(const bf16x8*)&pw[rowq * PS_LD + t2 * 32 + koff];
      for (int nd = 0; nd < 8; ++nd) {
        bf16x8 vb = *(const bf16x8*)&Vts[(nd * 16 + rowq) * VS_LD + t2 * 32 + koff];
        oacc[nd] = __builtin_amdgcn_mfma_f32_16x16x32_bf16(pa, vb, oacc[nd], 0, 0, 0);
      }
    }
  }

  float linv[4];
  for (int r = 0; r < 4; ++r) linv[r] = __builtin_amdgcn_rcpf(l_r[r]);
  for (int nd = 0; nd < 8; ++nd) {
    int col = h * HD_ + nd * 16 + rowq;
    for (int r = 0; r < 4; ++r) {
      int row = q0 + w * 16 + lr0 + r;
      Ob[(size_t)(b * S_ + row) * HID_ + col] = f2bf(oacc[nd][r] * linv[r]);
    }
  }
}

// ---------------- launcher ----------------
extern "C" void kernel_launch(void* const* d_in, const int* in_sizes, int n_in,
                              void* d_out, int out_size, void* d_ws, size_t ws_size,
                              hipStream_t stream) {
  (void)in_sizes; (void)n_in; (void)out_size; (void)ws_size;
  const float* hidden = (const float*)d_in[0];
  // d_in[1] = attention_mask (causal; reproduced analytically)
  const int* pos = (const int*)d_in[2];
  const float* Wq = (const float*)d_in[3];
  const float* Wk = (const float*)d_in[4];
  const float* Wv = (const float*)d_in[5];
  const float* Wo = (const float*)d_in[6];
  float* out = (float*)d_out;

  char* ws = (char*)d_ws;
  unsigned short* Xb   = (unsigned short*)(ws);               // 16 MB  (B,S,HID) bf16
  unsigned short* Wqb  = (unsigned short*)(ws + 16777216);    // 8 MB  Wq -- Wqb/Wkb/Wvb contiguous:
  unsigned short* Wkb  = (unsigned short*)(ws + 25165824);    // 8 MB  Wk -- one (6144,2048) QKV weight
  unsigned short* Wvb  = (unsigned short*)(ws + 33554432);    // 8 MB  Wv
  unsigned short* Wob  = (unsigned short*)(ws + 41943040);    // 8 MB
  unsigned short* Qb   = (unsigned short*)(ws + 50331648);    // 16 MB (B,NH,S,HD)
  unsigned short* Kb   = (unsigned short*)(ws + 67108864);    // 16 MB
  unsigned short* Vtmp = (unsigned short*)(ws + 83886080);    // 16 MB (B,S,HID)
  unsigned short* Vtb  = (unsigned short*)(ws + 100663296);   // 16 MB (B,NH,HD,S)
  unsigned short* Ob   = Xb;          // Xb dead after QKV GEMM
  float2* tbl          = (float2*)ws; // RoPE table also lives in dead Xb region (1 MB)

  cast_all<<<2048, 256, 0, stream>>>(hidden, Wq, Wk, Wv, Wo, Xb, Wqb, Wkb, Wvb, Wob);

  // fused QKV: C (4096 x 6144) = X (4096x2048) * Wqkv^T, 256x192 tiles
  dim3 gq(3 * HID_ / 192, (B_ * S_) / 256);  // (32, 16) = 512 blocks = exactly 2 rounds
  gemm_qkv<<<gq, 512, 0, stream>>>(Xb, Wqb, Qb, Kb, Vtmp);

  rope_table<<<(MAXTOK_ * 64) / 256, 256, 0, stream>>>(tbl);
  rope_apply<<<(B_ * NH_ * S_ * 64) / 256, 256, 0, stream>>>(Qb, Kb, pos, tbl);

  dim3 tg(S_ / 64, HD_ / 64, B_ * NH_);  // (32, 2, 32)
  transpose_v<<<tg, 256, 0, stream>>>(Vtmp, Vtb);

  dim3 ag(B_ * NH_, S_ / 64);  // bh fast, qt slow (descending inside kernel)
  attn_fused<<<ag, 256, 0, stream>>>(Qb, Kb, Vtb, Ob);

  dim3 go(HID_ / 128, (B_ * S_) / 128);  // (16, 32)
  gemm_out<<<go, 256, 0, stream>>>(Ob, Wob, out);
}